// Round 6
// baseline (198.086 us; speedup 1.0000x reference)
//
#include <hip/hip_runtime.h>

// Problem constants (B=2048, F=512, U=512, G=64, REG_STRENGTH=1.0)
#define B_SZ 2048
#define F_SZ 512
#define U_SZ 512
#define G_SZ 64
#define REG_STRENGTH 1.0f

// prep: histogram/prefix(shfl-scan)/scatter + workspace zeroing.
// gemm: block = (group g, 32-col tile ct). 128 thr = 2 waves x 16 cols.
//   Tile 32 cols x 32 rows x BK=64. 1024 blocks, 4 blocks/CU co-resident
//   (4 independent barrier domains per CU -- r4 had only 2).
//   2-step-ahead coalesced register prefetch (fits in 256-VGPR cap; r5's
//   identical schedule at 256thr spilled: WRITE_SIZE 4->108 MB, VGPR==cap),
//   bf16 hi/lo split -> XOR-swizzled LDS planes (double-buffered) -> MFMA.
//   In-loop barriers: `s_waitcnt lgkmcnt(0); s_barrier` -- prefetch loads
//   SURVIVE the barrier (T4); only the staged step's loads are vmcnt-waited.
#define THREADS 128
#define NCT 16              // 32-col tiles per group
#define NBLOCKS (G_SZ * NCT)  // 1024
#define MC 32               // M rows per chunk (cnt ~ Binom(2048,1/64) ~ 32)
#define BK 64               // K per step
#define NSTEP (F_SZ / BK)   // 8

typedef float f32x4 __attribute__((ext_vector_type(4)));
typedef __bf16 bf16x8 __attribute__((ext_vector_type(8)));

#define MFMA(a, b, c) __builtin_amdgcn_mfma_f32_16x16x32_bf16((a), (b), (c), 0, 0, 0)

// Seal LDS writes for cross-wave visibility WITHOUT draining vmcnt.
#define BARRIER_LGKM() \
  asm volatile("s_waitcnt lgkmcnt(0)\n\ts_barrier" ::: "memory")

// fp32 -> (hi, lo) bf16 split (RNE). Dropped lo*lo matmul term is O(2^-18):
// fp32-grade accuracy (verified r1-r5, absmax 0.015625 every round).
static __device__ __forceinline__ void split4(const f32x4 v, ushort4* h,
                                              ushort4* l) {
  unsigned short hb[4], lb[4];
#pragma unroll
  for (int i = 0; i < 4; ++i) {
    const __bf16 t = (__bf16)v[i];
    hb[i] = __builtin_bit_cast(unsigned short, t);
    lb[i] = __builtin_bit_cast(unsigned short, (__bf16)(v[i] - (float)t));
  }
  *h = make_ushort4(hb[0], hb[1], hb[2], hb[3]);
  *l = make_ushort4(lb[0], lb[1], lb[2], lb[3]);
}

// Stage one f32x4 into hi/lo LDS planes (row stride 128 B, XOR swizzle).
static __device__ __forceinline__ void stage4(unsigned short* __restrict__ H,
                                              unsigned short* __restrict__ L,
                                              int row, int kq, const f32x4 v) {
  int byte = (row << 7) + (kq << 3);
  byte ^= (row & 7) << 4;
  ushort4 h, l;
  split4(v, &h, &l);
  *(ushort4*)((char*)H + byte) = h;
  *(ushort4*)((char*)L + byte) = l;
}

// ---------------------------------------------------------------------------
// Kernel A: histogram -> shfl scan -> scatter; zeroes wsf/done.
// ---------------------------------------------------------------------------
__global__ __launch_bounds__(1024) void prep_kernel(
    const int* __restrict__ gid, int* __restrict__ counts,
    int* __restrict__ rowstart, int* __restrict__ order,
    float* __restrict__ wsf, unsigned* __restrict__ done) {
  __shared__ int cnt_s[G_SZ];
  __shared__ int cur_s[G_SZ];
  const int tid = threadIdx.x;

  if (tid < G_SZ) cnt_s[tid] = 0;
  if (tid == 0) { wsf[0] = 0.0f; *done = 0u; }
  __syncthreads();

  for (int b = tid; b < B_SZ; b += 1024) atomicAdd(&cnt_s[gid[b]], 1);
  __syncthreads();

  if (tid < G_SZ) {  // wave 0: shfl inclusive scan -> exclusive
    const int c = cnt_s[tid];
    int inc = c;
#pragma unroll
    for (int o = 1; o < G_SZ; o <<= 1) {
      const int t = __shfl_up(inc, o, 64);
      if (tid >= o) inc += t;
    }
    counts[tid] = c;
    rowstart[tid] = inc - c;
    cur_s[tid] = inc - c;
  }
  __syncthreads();

  for (int b = tid; b < B_SZ; b += 1024) {
    int pos = atomicAdd(&cur_s[gid[b]], 1);
    order[pos] = b;
  }
}

// ---------------------------------------------------------------------------
// One M-chunk: 2-deep register prefetch, counted barriers, double-buffered
// swizzled LDS, 3x MFMA split-bf16. All prefetch indices static (rule #20).
// ---------------------------------------------------------------------------
template <bool DOREG>
static __device__ __forceinline__ void run_chunk(
    const float* __restrict__ x, const int* __restrict__ order, int rs,
    int mc, int cnt, const float* __restrict__ wgp,
    const float* __restrict__ w0p, unsigned short* __restrict__ WH0,
    unsigned short* __restrict__ WH1, unsigned short* __restrict__ WL0,
    unsigned short* __restrict__ WL1, unsigned short* __restrict__ XH0,
    unsigned short* __restrict__ XH1, unsigned short* __restrict__ XL0,
    unsigned short* __restrict__ XL1, int srow, int kq, int wv, int llo,
    int lhi, const float* __restrict__ b_mu, int g, int mycol,
    float* __restrict__ out, float& regp) {
  const int rc = min(MC, cnt - mc);
  const int mts = (rc + 15) >> 4;  // active 16-row m-tiles (1 or 2)

  const float* xp[4];
#pragma unroll
  for (int u = 0; u < 4; ++u) {
    int sl = mc + srow + (u << 3);
    if (sl >= cnt) sl = cnt - 1;  // dup row; guarded at store
    xp[u] = x + (size_t)order[rs + sl] * F_SZ + (kq << 2);
  }

  f32x4 acc[2];
#pragma unroll
  for (int m = 0; m < 2; ++m) acc[m] = (f32x4){0.f, 0.f, 0.f, 0.f};

  unsigned short* const WH[2] = {WH0, WH1};
  unsigned short* const WL[2] = {WL0, WL1};
  unsigned short* const XH[2] = {XH0, XH1};
  unsigned short* const XL[2] = {XL0, XL1};

  // ---- prologue: issue loads for steps 0,1; stage step 0 -> buf 0 ----
  f32x4 wr[2][4], xr[2][4], zr[2][4];
#pragma unroll
  for (int d = 0; d < 2; ++d) {
    const int ko = d << 6;
#pragma unroll
    for (int u = 0; u < 4; ++u)
      wr[d][u] = *(const f32x4*)(wgp + (u << 12) + ko);
#pragma unroll
    for (int u = 0; u < 4; ++u) xr[d][u] = *(const f32x4*)(xp[u] + ko);
    if (DOREG) {
#pragma unroll
      for (int u = 0; u < 4; ++u)
        zr[d][u] = *(const f32x4*)(w0p + (u << 12) + ko);
    }
  }
#pragma unroll
  for (int u = 0; u < 4; ++u) {
    const int row = srow + (u << 3);
    stage4(WH[0], WL[0], row, kq, wr[0][u]);
    stage4(XH[0], XL[0], row, kq, xr[0][u]);
    if (DOREG) {
#pragma unroll
      for (int i = 0; i < 4; ++i) {
        const float d = wr[0][u][i] - zr[0][u][i];
        regp += d * d;
      }
    }
  }
  BARRIER_LGKM();

  // ---- steady state: 8 unrolled steps, static set/buffer indices ----
#pragma unroll
  for (int s = 0; s < NSTEP; ++s) {
    const int cs = s & 1;   // compute buffer / freed register set
    const int ns = cs ^ 1;  // next-staged register set / buffer
    // phase 1: issue loads for step s+2 into the freed set (survive barriers)
    if (s + 2 < NSTEP) {
      const int ko = (s + 2) << 6;
#pragma unroll
      for (int u = 0; u < 4; ++u)
        wr[cs][u] = *(const f32x4*)(wgp + (u << 12) + ko);
#pragma unroll
      for (int u = 0; u < 4; ++u) xr[cs][u] = *(const f32x4*)(xp[u] + ko);
      if (DOREG) {
#pragma unroll
        for (int u = 0; u < 4; ++u)
          zr[cs][u] = *(const f32x4*)(w0p + (u << 12) + ko);
      }
    }
    // phase 2: compute on buf cs (fragments from swizzled LDS)
    __builtin_amdgcn_s_setprio(1);
#pragma unroll
    for (int kk = 0; kk < 2; ++kk) {
      const int wrow = (wv << 4) + llo;
      int wb = (wrow << 7) + (kk << 6) + (lhi << 4);
      wb ^= (wrow & 7) << 4;
      const bf16x8 wh = *(const bf16x8*)((const char*)WH[cs] + wb);
      const bf16x8 wl = *(const bf16x8*)((const char*)WL[cs] + wb);
#pragma unroll
      for (int m = 0; m < 2; ++m) {
        if (m < mts) {
          const int ar = (m << 4) + llo;
          int ab = (ar << 7) + (kk << 6) + (lhi << 4);
          ab ^= (ar & 7) << 4;
          const bf16x8 ah = *(const bf16x8*)((const char*)XH[cs] + ab);
          const bf16x8 al = *(const bf16x8*)((const char*)XL[cs] + ab);
          acc[m] = MFMA(ah, wh, acc[m]);
          acc[m] = MFMA(ah, wl, acc[m]);
          acc[m] = MFMA(al, wh, acc[m]);
        }
      }
    }
    __builtin_amdgcn_s_setprio(0);
    // phase 3 (write-late): stage step s+1 (set ns) into buf ns; W reg-loss.
    // vmcnt wait here covers only set ns's loads (s+2's stay outstanding).
    if (s + 1 < NSTEP) {
#pragma unroll
      for (int u = 0; u < 4; ++u) {
        const int row = srow + (u << 3);
        stage4(WH[ns], WL[ns], row, kq, wr[ns][u]);
        stage4(XH[ns], XL[ns], row, kq, xr[ns][u]);
        if (DOREG) {
#pragma unroll
          for (int i = 0; i < 4; ++i) {
            const float d = wr[ns][u][i] - zr[ns][u][i];
            regp += d * d;
          }
        }
      }
    }
    // phase 4: seal LDS; vmcnt NOT drained
    BARRIER_LGKM();
  }

  // ---- epilogue: D row = 4*lhi + j, col = llo; scatter by order ----
  const float bias = b_mu[(g << 9) + mycol];
#pragma unroll
  for (int m = 0; m < 2; ++m) {
    if (m < mts) {
#pragma unroll
      for (int j = 0; j < 4; ++j) {
        const int slot = mc + (m << 4) + (lhi << 2) + j;
        if (slot < cnt) {
          out[(size_t)order[rs + slot] * U_SZ + mycol] = acc[m][j] + bias;
        }
      }
    }
  }
}

// ---------------------------------------------------------------------------
// Kernel B: grouped GEMM (LDS-staged MFMA) + fused reg loss + finalize.
// ---------------------------------------------------------------------------
__global__ __launch_bounds__(THREADS, 2) void gemm_kernel(
    const float* __restrict__ x, const float* __restrict__ w_mu,
    const float* __restrict__ b_mu, const float* __restrict__ w0_mu,
    const float* __restrict__ b0_mu, float* __restrict__ out,
    float* __restrict__ wsf, unsigned* __restrict__ done,
    const int* __restrict__ counts, const int* __restrict__ rowstart,
    const int* __restrict__ order) {
  // bf16 planes, 32 rows x 64 k, double-buffered: 8 planes x 4 KB = 32 KB.
  __shared__ __align__(16) unsigned short WH[2][MC * BK];
  __shared__ __align__(16) unsigned short WL[2][MC * BK];
  __shared__ __align__(16) unsigned short XH[2][MC * BK];
  __shared__ __align__(16) unsigned short XL[2][MC * BK];
  __shared__ float red_s[2];

  const int bid = blockIdx.x;
  const int g = bid & 63;   // bid%8 == g%8 -> a group's blocks share an XCD
  const int ct = bid >> 6;  // 32-col tile 0..15
  const int n0 = ct << 5;

  const int tid = threadIdx.x;
  const int lane = tid & 63;
  const int wv = tid >> 6;    // wave 0..1 -> 16-col slice
  const int llo = lane & 15;  // frag row/col within 16-tile
  const int lhi = lane >> 4;  // frag k-subchunk

  const int srow = tid >> 4;  // staging: row base 0..7 (u adds 8,16,24)
  const int kq = tid & 15;    // staging: float4 within row (coalesced)

  const int cnt = counts[g];

  if (cnt > 0) {
    const int rs = rowstart[g];
    const int mycol = n0 + (wv << 4) + llo;
    const float* __restrict__ wgp =
        w_mu + ((size_t)g << 18) + (size_t)(n0 + srow) * F_SZ + (kq << 2);
    const float* __restrict__ w0p =
        w0_mu + (size_t)(n0 + srow) * F_SZ + (kq << 2);

    float regp = 0.0f;
    if (ct == 0) {  // fused bias reg-loss, once per group
#pragma unroll
      for (int u = 0; u < 4; ++u) {
        const int idx = (u << 7) + tid;
        const float d = b_mu[(g << 9) + idx] - b0_mu[idx];
        regp += d * d;
      }
    }

    for (int mc = 0; mc < cnt; mc += MC) {  // 1-2 passes (cnt ~ 32)
      if (mc == 0) {
        run_chunk<true>(x, order, rs, 0, cnt, wgp, w0p, WH[0], WH[1], WL[0],
                        WL[1], XH[0], XH[1], XL[0], XL[1], srow, kq, wv, llo,
                        lhi, b_mu, g, mycol, out, regp);
      } else {
        run_chunk<false>(x, order, rs, mc, cnt, wgp, w0p, WH[0], WH[1], WL[0],
                         WL[1], XH[0], XH[1], XL[0], XL[1], srow, kq, wv, llo,
                         lhi, b_mu, g, mycol, out, regp);
      }
    }

    // ---- block-reduce reg partials, weight by cnt, one atomic ----
#pragma unroll
    for (int o = 32; o > 0; o >>= 1) regp += __shfl_down(regp, o, 64);
    if (lane == 0) red_s[wv] = regp;
    __syncthreads();
    if (tid == 0) atomicAdd(wsf, (float)cnt * (red_s[0] + red_s[1]));
  }

  // fused finalize: last block writes the reg-loss scalar
  if (tid == 0) {
    __threadfence();
    if (atomicAdd(done, 1u) == (unsigned)(NBLOCKS - 1)) {
      const float v = atomicAdd(wsf, 0.0f);  // coherent device-scope read
      out[(size_t)B_SZ * U_SZ] = REG_STRENGTH * v;
    }
  }
}

extern "C" void kernel_launch(void* const* d_in, const int* in_sizes, int n_in,
                              void* d_out, int out_size, void* d_ws,
                              size_t ws_size, hipStream_t stream) {
  (void)in_sizes; (void)n_in; (void)out_size; (void)ws_size;
  const float* x     = (const float*)d_in[0];
  const int*   gid   = (const int*)d_in[1];
  const float* w_mu  = (const float*)d_in[2];
  const float* b_mu  = (const float*)d_in[3];
  const float* w0_mu = (const float*)d_in[4];
  const float* b0_mu = (const float*)d_in[5];

  float*    wsf      = (float*)d_ws;         // [0]
  unsigned* done     = (unsigned*)d_ws + 1;  // [1]
  int*      counts   = (int*)d_ws + 2;
  int*      rowstart = (int*)d_ws + 2 + G_SZ;
  int*      order    = (int*)d_ws + 2 + 2 * G_SZ;

  prep_kernel<<<1, 1024, 0, stream>>>(gid, counts, rowstart, order, wsf, done);
  gemm_kernel<<<NBLOCKS, THREADS, 0, stream>>>(
      x, w_mu, b_mu, w0_mu, b0_mu, (float*)d_out, wsf, done,
      counts, rowstart, order);
}

// Round 7
// 187.211 us; speedup vs baseline: 1.0581x; 1.0581x over previous
//
#include <hip/hip_runtime.h>

// Problem constants (B=2048, F=512, U=512, G=64, REG_STRENGTH=1.0)
#define B_SZ 2048
#define F_SZ 512
#define U_SZ 512
#define G_SZ 64
#define REG_STRENGTH 1.0f

// prep: histogram/prefix(shfl-scan)/scatter + workspace zeroing.
// gemm: block = (group g, 64-col tile nt), 256 thr = 4 waves (r4 skeleton,
//   the proven non-spilling build: VGPR 108, WRITE 4.1 MB, 43.5 us).
//   This round: 2-step-ahead register prefetch with HAND-INSTANTIATED
//   gemm_step<S> (S=0..7 explicit) and NAMED register sets A/B -- no
//   runtime-indexable arrays anywhere (rule #20: r5/r6's wr[cs] pipelines
//   were allocated in scratch: VGPR=128 + 190 MB scratch traffic).
//   In-loop barrier = `s_waitcnt lgkmcnt(0); s_barrier`: LDS sealed, global
//   prefetch loads SURVIVE the barrier (T4). The asm memory clobber also
//   pins each step's loads before its barrier -> schedule is enforced.
#define THREADS 256
#define NBLOCKS 512        // bid%8 == g%8: a group's 8 blocks share an XCD
#define MC 64              // M rows per chunk (cnt ~ Binom(2048,1/64) ~ 32)
#define BK 64              // K per step
#define NSTEP (F_SZ / BK)  // 8

typedef float f32x4 __attribute__((ext_vector_type(4)));
typedef __bf16 bf16x8 __attribute__((ext_vector_type(8)));

#define MFMA(a, b, c) __builtin_amdgcn_mfma_f32_16x16x32_bf16((a), (b), (c), 0, 0, 0)

// Seal LDS writes for cross-wave visibility WITHOUT draining vmcnt.
#define BARRIER_LGKM() \
  asm volatile("s_waitcnt lgkmcnt(0)\n\ts_barrier" ::: "memory")

// fp32 -> (hi, lo) bf16 split (RNE). Dropped lo*lo matmul term is O(2^-18):
// fp32-grade accuracy (verified r1-r6, absmax 0.015625 every round).
static __device__ __forceinline__ void split4(const f32x4 v, ushort4* h,
                                              ushort4* l) {
  unsigned short hb[4], lb[4];
#pragma unroll
  for (int i = 0; i < 4; ++i) {
    const __bf16 t = (__bf16)v[i];
    hb[i] = __builtin_bit_cast(unsigned short, t);
    lb[i] = __builtin_bit_cast(unsigned short, (__bf16)(v[i] - (float)t));
  }
  *h = make_ushort4(hb[0], hb[1], hb[2], hb[3]);
  *l = make_ushort4(lb[0], lb[1], lb[2], lb[3]);
}

// Stage one f32x4 into hi/lo LDS planes (row stride 128 B, XOR swizzle).
static __device__ __forceinline__ void stage4(unsigned short* __restrict__ H,
                                              unsigned short* __restrict__ L,
                                              int row, int kq, const f32x4 v) {
  int byte = (row << 7) + (kq << 3);
  byte ^= (row & 7) << 4;
  ushort4 h, l;
  split4(v, &h, &l);
  *(ushort4*)((char*)H + byte) = h;
  *(ushort4*)((char*)L + byte) = l;
}

struct Bufs {
  unsigned short* WH0; unsigned short* WL0;
  unsigned short* XH0; unsigned short* XL0;
  unsigned short* WH1; unsigned short* WL1;
  unsigned short* XH1; unsigned short* XL1;
};

// ---------------------------------------------------------------------------
// Kernel A: histogram -> shfl scan -> scatter; zeroes wsf/done.
// ---------------------------------------------------------------------------
__global__ __launch_bounds__(1024) void prep_kernel(
    const int* __restrict__ gid, int* __restrict__ counts,
    int* __restrict__ rowstart, int* __restrict__ order,
    float* __restrict__ wsf, unsigned* __restrict__ done) {
  __shared__ int cnt_s[G_SZ];
  __shared__ int cur_s[G_SZ];
  const int tid = threadIdx.x;

  if (tid < G_SZ) cnt_s[tid] = 0;
  if (tid == 0) { wsf[0] = 0.0f; *done = 0u; }
  __syncthreads();

  for (int b = tid; b < B_SZ; b += 1024) atomicAdd(&cnt_s[gid[b]], 1);
  __syncthreads();

  if (tid < G_SZ) {  // wave 0: shfl inclusive scan -> exclusive
    const int c = cnt_s[tid];
    int inc = c;
#pragma unroll
    for (int o = 1; o < G_SZ; o <<= 1) {
      const int t = __shfl_up(inc, o, 64);
      if (tid >= o) inc += t;
    }
    counts[tid] = c;
    rowstart[tid] = inc - c;
    cur_s[tid] = inc - c;
  }
  __syncthreads();

  for (int b = tid; b < B_SZ; b += 1024) {
    int pos = atomicAdd(&cur_s[gid[b]], 1);
    order[pos] = b;
  }
}

// ---------------------------------------------------------------------------
// One pipeline step S (compile-time): issue loads for S+2 into the freed set,
// stage set holding S+1 into buf[(S+1)&1] (write-late), MFMA on buf[S&1],
// counted barrier. All buffer/set selection is compile-time.
// ---------------------------------------------------------------------------
template <int S, bool DOREG>
static __device__ __forceinline__ void gemm_step(
    const Bufs& B, const float* __restrict__ wgp,
    const float* __restrict__ w0p, const float* const (&xp)[4],
    f32x4 (&wr_i)[4], f32x4 (&xr_i)[4], f32x4 (&zr_i)[4],  // issue target
    f32x4 (&wr_s)[4], f32x4 (&xr_s)[4], f32x4 (&zr_s)[4],  // holds S+1 data
    int srow, int kq, int wv, int llo, int lhi, int mts,
    f32x4 (&acc)[4], float& regp) {
  // phase 1: issue loads for step S+2 (they out-live the barriers below)
  if constexpr (S + 2 < NSTEP) {
    constexpr int ko = (S + 2) * BK;
#pragma unroll
    for (int u = 0; u < 4; ++u)
      wr_i[u] = *(const f32x4*)(wgp + (u << 13) + ko);
#pragma unroll
    for (int u = 0; u < 4; ++u) xr_i[u] = *(const f32x4*)(xp[u] + ko);
    if (DOREG) {
#pragma unroll
      for (int u = 0; u < 4; ++u)
        zr_i[u] = *(const f32x4*)(w0p + (u << 13) + ko);
    }
  }
  // phase 2: stage step S+1 into buf[(S+1)&1]; fused W reg-loss.
  // vmcnt wait here covers loads issued 2 steps ago (~2 compute phases).
  if constexpr (S + 1 < NSTEP) {
    unsigned short* const WHn = ((S + 1) & 1) ? B.WH1 : B.WH0;
    unsigned short* const WLn = ((S + 1) & 1) ? B.WL1 : B.WL0;
    unsigned short* const XHn = ((S + 1) & 1) ? B.XH1 : B.XH0;
    unsigned short* const XLn = ((S + 1) & 1) ? B.XL1 : B.XL0;
#pragma unroll
    for (int u = 0; u < 4; ++u) {
      const int row = srow + (u << 4);
      stage4(WHn, WLn, row, kq, wr_s[u]);
      stage4(XHn, XLn, row, kq, xr_s[u]);
      if (DOREG) {
#pragma unroll
        for (int i = 0; i < 4; ++i) {
          const float d = wr_s[u][i] - zr_s[u][i];
          regp += d * d;
        }
      }
    }
  }
  // phase 3: compute on buf[S&1] (sealed by the previous barrier); the MFMA
  // cluster overlaps the ds_writes above (different buffers).
  const unsigned short* const WHc = (S & 1) ? B.WH1 : B.WH0;
  const unsigned short* const WLc = (S & 1) ? B.WL1 : B.WL0;
  const unsigned short* const XHc = (S & 1) ? B.XH1 : B.XH0;
  const unsigned short* const XLc = (S & 1) ? B.XL1 : B.XL0;
  __builtin_amdgcn_s_setprio(1);
#pragma unroll
  for (int kk = 0; kk < 2; ++kk) {
    const int wrow = (wv << 4) + llo;
    int wb = (wrow << 7) + (kk << 6) + (lhi << 4);
    wb ^= (wrow & 7) << 4;
    const bf16x8 wh = *(const bf16x8*)((const char*)WHc + wb);
    const bf16x8 wl = *(const bf16x8*)((const char*)WLc + wb);
#pragma unroll
    for (int m = 0; m < 4; ++m) {
      if (m < mts) {
        const int ar = (m << 4) + llo;
        int ab = (ar << 7) + (kk << 6) + (lhi << 4);
        ab ^= (ar & 7) << 4;
        const bf16x8 ah = *(const bf16x8*)((const char*)XHc + ab);
        const bf16x8 al = *(const bf16x8*)((const char*)XLc + ab);
        acc[m] = MFMA(ah, wh, acc[m]);
        acc[m] = MFMA(ah, wl, acc[m]);
        acc[m] = MFMA(al, wh, acc[m]);
      }
    }
  }
  __builtin_amdgcn_s_setprio(0);
  // phase 4: seal LDS writes; vmcnt NOT drained (S+2 loads stay in flight)
  BARRIER_LGKM();
}

// ---------------------------------------------------------------------------
// One M-chunk: prologue + 8 explicit steps (named sets A/B alternate).
// ---------------------------------------------------------------------------
template <bool DOREG>
static __device__ __forceinline__ void run_chunk(
    const float* __restrict__ x, const int* __restrict__ order, int rs,
    int mc, int cnt, const float* __restrict__ wgp,
    const float* __restrict__ w0p, const Bufs& B, int srow, int kq, int wv,
    int llo, int lhi, const float* __restrict__ b_mu, int g, int mycol,
    float* __restrict__ out, float& regp) {
  const int rc = min(MC, cnt - mc);
  const int mts = (rc + 15) >> 4;  // active 16-row m-tiles (1..4)

  const float* xp[4];
#pragma unroll
  for (int u = 0; u < 4; ++u) {
    int sl = mc + srow + (u << 4);
    if (sl >= cnt) sl = cnt - 1;  // dup row; guarded at store
    xp[u] = x + (size_t)order[rs + sl] * F_SZ + (kq << 2);
  }

  f32x4 acc[4];
#pragma unroll
  for (int m = 0; m < 4; ++m) acc[m] = (f32x4){0.f, 0.f, 0.f, 0.f};

  // named register sets (never runtime-indexed)
  f32x4 wrA[4], xrA[4], zrA[4], wrB[4], xrB[4], zrB[4];

  // ---- prologue: load step0 -> A, step1 -> B; stage A -> buf0 ----
#pragma unroll
  for (int u = 0; u < 4; ++u) wrA[u] = *(const f32x4*)(wgp + (u << 13));
#pragma unroll
  for (int u = 0; u < 4; ++u) xrA[u] = *(const f32x4*)(xp[u]);
  if (DOREG) {
#pragma unroll
    for (int u = 0; u < 4; ++u) zrA[u] = *(const f32x4*)(w0p + (u << 13));
  }
#pragma unroll
  for (int u = 0; u < 4; ++u)
    wrB[u] = *(const f32x4*)(wgp + (u << 13) + BK);
#pragma unroll
  for (int u = 0; u < 4; ++u) xrB[u] = *(const f32x4*)(xp[u] + BK);
  if (DOREG) {
#pragma unroll
    for (int u = 0; u < 4; ++u)
      zrB[u] = *(const f32x4*)(w0p + (u << 13) + BK);
  }
#pragma unroll
  for (int u = 0; u < 4; ++u) {
    const int row = srow + (u << 4);
    stage4(B.WH0, B.WL0, row, kq, wrA[u]);
    stage4(B.XH0, B.XL0, row, kq, xrA[u]);
    if (DOREG) {
#pragma unroll
      for (int i = 0; i < 4; ++i) {
        const float d = wrA[u][i] - zrA[u][i];
        regp += d * d;
      }
    }
  }
  BARRIER_LGKM();

  // ---- 8 explicit steps; issue set = set[S&1], stage set = set[(S+1)&1] ----
  gemm_step<0, DOREG>(B, wgp, w0p, xp, wrA, xrA, zrA, wrB, xrB, zrB, srow, kq,
                      wv, llo, lhi, mts, acc, regp);
  gemm_step<1, DOREG>(B, wgp, w0p, xp, wrB, xrB, zrB, wrA, xrA, zrA, srow, kq,
                      wv, llo, lhi, mts, acc, regp);
  gemm_step<2, DOREG>(B, wgp, w0p, xp, wrA, xrA, zrA, wrB, xrB, zrB, srow, kq,
                      wv, llo, lhi, mts, acc, regp);
  gemm_step<3, DOREG>(B, wgp, w0p, xp, wrB, xrB, zrB, wrA, xrA, zrA, srow, kq,
                      wv, llo, lhi, mts, acc, regp);
  gemm_step<4, DOREG>(B, wgp, w0p, xp, wrA, xrA, zrA, wrB, xrB, zrB, srow, kq,
                      wv, llo, lhi, mts, acc, regp);
  gemm_step<5, DOREG>(B, wgp, w0p, xp, wrB, xrB, zrB, wrA, xrA, zrA, srow, kq,
                      wv, llo, lhi, mts, acc, regp);
  gemm_step<6, DOREG>(B, wgp, w0p, xp, wrA, xrA, zrA, wrB, xrB, zrB, srow, kq,
                      wv, llo, lhi, mts, acc, regp);
  gemm_step<7, DOREG>(B, wgp, w0p, xp, wrB, xrB, zrB, wrA, xrA, zrA, srow, kq,
                      wv, llo, lhi, mts, acc, regp);

  // ---- epilogue: D row = 4*lhi + j, col = llo; scatter by order ----
  const float bias = b_mu[(g << 9) + mycol];
#pragma unroll
  for (int m = 0; m < 4; ++m) {
    if (m < mts) {
#pragma unroll
      for (int j = 0; j < 4; ++j) {
        const int slot = mc + (m << 4) + (lhi << 2) + j;
        if (slot < cnt) {
          out[(size_t)order[rs + slot] * U_SZ + mycol] = acc[m][j] + bias;
        }
      }
    }
  }
}

// ---------------------------------------------------------------------------
// Kernel B: grouped GEMM (LDS-staged MFMA) + fused reg loss + finalize.
// ---------------------------------------------------------------------------
__global__ __launch_bounds__(THREADS, 2) void gemm_kernel(
    const float* __restrict__ x, const float* __restrict__ w_mu,
    const float* __restrict__ b_mu, const float* __restrict__ w0_mu,
    const float* __restrict__ b0_mu, float* __restrict__ out,
    float* __restrict__ wsf, unsigned* __restrict__ done,
    const int* __restrict__ counts, const int* __restrict__ rowstart,
    const int* __restrict__ order) {
  // bf16 planes, 64 rows x 64 k, double-buffered: 8 planes x 8 KB = 64 KB.
  __shared__ __align__(16) unsigned short WH[2][MC * BK];
  __shared__ __align__(16) unsigned short WL[2][MC * BK];
  __shared__ __align__(16) unsigned short XH[2][MC * BK];
  __shared__ __align__(16) unsigned short XL[2][MC * BK];
  __shared__ float red_s[4];

  const Bufs B = {WH[0], WL[0], XH[0], XL[0], WH[1], WL[1], XH[1], XL[1]};

  const int bid = blockIdx.x;
  const int g = bid & 63;   // bid%8 == g%8 -> a group's blocks share an XCD
  const int nt = bid >> 6;  // 64-col tile 0..7
  const int n0 = nt << 6;

  const int tid = threadIdx.x;
  const int lane = tid & 63;
  const int wv = tid >> 6;    // wave -> 16-col slice
  const int llo = lane & 15;  // frag row/col within 16-tile
  const int lhi = lane >> 4;  // frag k-subchunk

  const int srow = tid >> 4;  // staging: row base 0..15 (u adds 16,32,48)
  const int kq = tid & 15;    // staging: float4 within row (coalesced)

  const int cnt = counts[g];

  if (cnt > 0) {
    const int rs = rowstart[g];
    const int mycol = n0 + (wv << 4) + llo;
    const float* __restrict__ wgp =
        w_mu + ((size_t)g << 18) + (size_t)(n0 + srow) * F_SZ + (kq << 2);
    const float* __restrict__ w0p =
        w0_mu + (size_t)(n0 + srow) * F_SZ + (kq << 2);

    float regp = 0.0f;
    if (nt == 0) {  // fused bias reg-loss, once per group
#pragma unroll
      for (int u = 0; u < 2; ++u) {
        const int idx = (u << 8) + tid;
        const float d = b_mu[(g << 9) + idx] - b0_mu[idx];
        regp += d * d;
      }
    }

    for (int mc = 0; mc < cnt; mc += MC) {  // one pass in practice (cnt<=64)
      if (mc == 0) {
        run_chunk<true>(x, order, rs, 0, cnt, wgp, w0p, B, srow, kq, wv, llo,
                        lhi, b_mu, g, mycol, out, regp);
      } else {
        run_chunk<false>(x, order, rs, mc, cnt, wgp, w0p, B, srow, kq, wv,
                         llo, lhi, b_mu, g, mycol, out, regp);
      }
    }

    // ---- block-reduce reg partials, weight by cnt, one atomic ----
#pragma unroll
    for (int o = 32; o > 0; o >>= 1) regp += __shfl_down(regp, o, 64);
    if (lane == 0) red_s[wv] = regp;
    __syncthreads();
    if (tid == 0)
      atomicAdd(wsf, (float)cnt * (red_s[0] + red_s[1] + red_s[2] + red_s[3]));
  }

  // fused finalize: last block writes the reg-loss scalar
  if (tid == 0) {
    __threadfence();
    if (atomicAdd(done, 1u) == (unsigned)(NBLOCKS - 1)) {
      const float v = atomicAdd(wsf, 0.0f);  // coherent device-scope read
      out[(size_t)B_SZ * U_SZ] = REG_STRENGTH * v;
    }
  }
}

extern "C" void kernel_launch(void* const* d_in, const int* in_sizes, int n_in,
                              void* d_out, int out_size, void* d_ws,
                              size_t ws_size, hipStream_t stream) {
  (void)in_sizes; (void)n_in; (void)out_size; (void)ws_size;
  const float* x     = (const float*)d_in[0];
  const int*   gid   = (const int*)d_in[1];
  const float* w_mu  = (const float*)d_in[2];
  const float* b_mu  = (const float*)d_in[3];
  const float* w0_mu = (const float*)d_in[4];
  const float* b0_mu = (const float*)d_in[5];

  float*    wsf      = (float*)d_ws;         // [0]
  unsigned* done     = (unsigned*)d_ws + 1;  // [1]
  int*      counts   = (int*)d_ws + 2;
  int*      rowstart = (int*)d_ws + 2 + G_SZ;
  int*      order    = (int*)d_ws + 2 + 2 * G_SZ;

  prep_kernel<<<1, 1024, 0, stream>>>(gid, counts, rowstart, order, wsf, done);
  gemm_kernel<<<NBLOCKS, THREADS, 0, stream>>>(
      x, w_mu, b_mu, w0_mu, b0_mu, (float*)d_out, wsf, done,
      counts, rowstart, order);
}

// Round 8
// 167.694 us; speedup vs baseline: 1.1812x; 1.1164x over previous
//
#include <hip/hip_runtime.h>

// Problem constants (B=2048, F=512, U=512, G=64, REG_STRENGTH=1.0)
#define B_SZ 2048
#define F_SZ 512
#define U_SZ 512
#define G_SZ 64
#define REG_STRENGTH 1.0f

// prep: histogram/prefix(shfl-scan)/scatter + workspace zeroing.
// gemm: block = (group g, 64-col tile nt), 256 thr = 4 waves x 16 cols.
//   Staging via global_load_lds (fp32, NO register round-trip): pipeline
//   state lives in LDS, not VGPRs -> nothing to spill (r5/r6/r7 lesson:
//   register prefetch arrays + asm barriers = 107 MB scratch traffic).
//   4 buffers x (W 8KB + X 8KB), BK=32, issue depth 3, counted
//   `s_waitcnt vmcnt(N); s_barrier` per step (T4: never drain in-loop).
//   Linear LDS dest + inverse-swizzled global src (kq ^ (row&7), rule #21);
//   fragment ds_read_b128 applies the same XOR -> conflict-free.
//   bf16 hi/lo split at READ time, 3x mfma_f32_16x16x32_bf16 (fp32-grade,
//   absmax 0.015625 every round since r1).
#define THREADS 256
#define NBLOCKS 512        // bid%8 == g%8: a group's 8 blocks share an XCD
#define MC 64              // M rows per chunk (cnt ~ Binom(2048,1/64) ~ 32)
#define BK 32              // K per step (one MFMA K-slice)
#define NSTEP (F_SZ / BK)  // 16

typedef float f32x4 __attribute__((ext_vector_type(4)));
typedef __bf16 bf16x8 __attribute__((ext_vector_type(8)));

#define MFMA(a, b, c) __builtin_amdgcn_mfma_f32_16x16x32_bf16((a), (b), (c), 0, 0, 0)

// Counted wait + barrier fused (nothing can slip between). vmcnt(N) only
// assumes: everything issued >= 2 iterations ago must drain -- robust to
// intra-iteration reordering of load issues by the compiler.
#define WAITBAR(N) \
  asm volatile("s_waitcnt vmcnt(" #N ")\n\ts_barrier" ::: "memory")
#define ISSUE_FENCE() asm volatile("" ::: "memory")

// Direct global->LDS 16B load. LDS dest is wave-uniform base + lane*16;
// global src is per-lane.
static __device__ __forceinline__ void gload16(const float* g, char* l) {
  __builtin_amdgcn_global_load_lds(
      (const __attribute__((address_space(1))) void*)g,
      (__attribute__((address_space(3))) void*)l, 16, 0, 0);
}

// fp32 -> (hi, lo) bf16 split of 8 values (RNE). Dropped lo*lo matmul term
// is O(2^-18): fp32-grade accuracy.
static __device__ __forceinline__ void cvt8(const f32x4 a, const f32x4 b,
                                            bf16x8& h, bf16x8& l) {
#pragma unroll
  for (int i = 0; i < 4; ++i) {
    const __bf16 t = (__bf16)a[i];
    h[i] = t;
    l[i] = (__bf16)(a[i] - (float)t);
  }
#pragma unroll
  for (int i = 0; i < 4; ++i) {
    const __bf16 t = (__bf16)b[i];
    h[4 + i] = t;
    l[4 + i] = (__bf16)(b[i] - (float)t);
  }
}

// ---------------------------------------------------------------------------
// Kernel A: histogram -> shfl scan -> scatter; zeroes wsf/done.
// ---------------------------------------------------------------------------
__global__ __launch_bounds__(1024) void prep_kernel(
    const int* __restrict__ gid, int* __restrict__ counts,
    int* __restrict__ rowstart, int* __restrict__ order,
    float* __restrict__ wsf, unsigned* __restrict__ done) {
  __shared__ int cnt_s[G_SZ];
  __shared__ int cur_s[G_SZ];
  const int tid = threadIdx.x;

  if (tid < G_SZ) cnt_s[tid] = 0;
  if (tid == 0) { wsf[0] = 0.0f; *done = 0u; }
  __syncthreads();

  for (int b = tid; b < B_SZ; b += 1024) atomicAdd(&cnt_s[gid[b]], 1);
  __syncthreads();

  if (tid < G_SZ) {  // wave 0: shfl inclusive scan -> exclusive
    const int c = cnt_s[tid];
    int inc = c;
#pragma unroll
    for (int o = 1; o < G_SZ; o <<= 1) {
      const int t = __shfl_up(inc, o, 64);
      if (tid >= o) inc += t;
    }
    counts[tid] = c;
    rowstart[tid] = inc - c;
    cur_s[tid] = inc - c;
  }
  __syncthreads();

  for (int b = tid; b < B_SZ; b += 1024) {
    int pos = atomicAdd(&cur_s[gid[b]], 1);
    order[pos] = b;
  }
}

// ---------------------------------------------------------------------------
// One pipeline step S (compile-time): counted wait+barrier, issue stage(S+3)
// via global_load_lds, compute step S from LDS buffer S&3, fused W reg-loss
// (LDS readback vs 2-deep w0 register pair).
// ---------------------------------------------------------------------------
template <int S, bool DOREG>
static __device__ __forceinline__ void step(
    char* SWb, char* SXb, const float* wgA, const float* wgB,
    const float* xgA, const float* xgB, const float* w0gA,
    const float* w0gB, f32x4& w0a0, f32x4& w0a1, f32x4& w0b0, f32x4& w0b1,
    int wv, int llo, int lhi, int tid, int mts, f32x4& acc0, f32x4& acc1,
    f32x4& acc2, f32x4& acc3, float& regp) {
  // counted wait + barrier: stage(S) (and w0(S) when DOREG) guaranteed done;
  // loads issued in the previous <=2 iterations stay IN FLIGHT.
  if constexpr (DOREG) {
    if constexpr (S < NSTEP - 2) WAITBAR(6);
    else if constexpr (S == NSTEP - 2) WAITBAR(2);
    else WAITBAR(0);
  } else {
    if constexpr (S < NSTEP - 2) WAITBAR(8);
    else if constexpr (S == NSTEP - 2) WAITBAR(4);
    else WAITBAR(0);
  }
  // issue stage(S+3): buffer (S+3)&3 was released by compute(S-1), which the
  // barrier above just sealed across all waves.
  if constexpr (S + 3 < NSTEP) {
    constexpr int T = S + 3;
    char* dw = SWb + (T & 3) * 8192 + (wv << 10);
    char* dx = SXb + (T & 3) * 8192 + (wv << 10);
    gload16(wgA + T * BK, dw);
    gload16(wgB + T * BK, dw + 4096);
    gload16(xgA + T * BK, dx);
    gload16(xgB + T * BK, dx + 4096);
  }
  // compute step S: fragments from swizzled fp32 LDS, split to bf16 hi/lo.
  const char* wpl = SWb + (S & 3) * 8192;
  const char* xpl = SXb + (S & 3) * 8192;
  const int wrow = (wv << 4) + llo;
  const int q0 = lhi << 1;
  const f32x4 w0f = *(const f32x4*)(wpl + wrow * 128 + ((q0 ^ (wrow & 7)) << 4));
  const f32x4 w1f =
      *(const f32x4*)(wpl + wrow * 128 + (((q0 + 1) ^ (wrow & 7)) << 4));
  bf16x8 wh, wl;
  cvt8(w0f, w1f, wh, wl);
#define ATILE(R_, ACC)                                                        \
  {                                                                           \
    const int r_ = (R_);                                                      \
    const f32x4 a0 = *(const f32x4*)(xpl + r_ * 128 + ((q0 ^ (r_ & 7)) << 4));\
    const f32x4 a1 =                                                          \
        *(const f32x4*)(xpl + r_ * 128 + (((q0 + 1) ^ (r_ & 7)) << 4));       \
    bf16x8 ah, al;                                                            \
    cvt8(a0, a1, ah, al);                                                     \
    ACC = MFMA(ah, wh, ACC);                                                  \
    ACC = MFMA(ah, wl, ACC);                                                  \
    ACC = MFMA(al, wh, ACC);                                                  \
  }
  ATILE(llo, acc0);
  if (mts > 1) ATILE(16 + llo, acc1);
  if (mts > 2) ATILE(32 + llo, acc2);
  if (mts > 3) ATILE(48 + llo, acc3);
#undef ATILE
  // fused W reg-loss: read back this thread's own staged fp32 W quads from
  // LDS (linear slots), compare against the prefetched w0 pair, then reload
  // the pair for step S+2 (anti-dependency keeps use-before-overwrite).
  if constexpr (DOREG) {
    const f32x4 sa = *(const f32x4*)(wpl + (tid << 4));
    const f32x4 sb = *(const f32x4*)(wpl + 4096 + (tid << 4));
    const f32x4& u0 = (S & 1) ? w0b0 : w0a0;
    const f32x4& u1 = (S & 1) ? w0b1 : w0a1;
#pragma unroll
    for (int i = 0; i < 4; ++i) {
      const float d0 = sa[i] - u0[i], d1 = sb[i] - u1[i];
      regp += d0 * d0 + d1 * d1;
    }
    if constexpr (S + 2 < NSTEP) {
      f32x4& t0 = (S & 1) ? w0b0 : w0a0;
      f32x4& t1 = (S & 1) ? w0b1 : w0a1;
      t0 = *(const f32x4*)(w0gA + (S + 2) * BK);
      t1 = *(const f32x4*)(w0gB + (S + 2) * BK);
    }
  }
}

// ---------------------------------------------------------------------------
// One M-chunk: prologue (3 stages + w0 pair) + 16 explicit steps + epilogue.
// ---------------------------------------------------------------------------
template <bool DOREG>
static __device__ __forceinline__ void run_chunk(
    const float* __restrict__ x, const int* __restrict__ order, int rs,
    int mc, int cnt, const float* wgA, const float* wgB, const float* w0gA,
    const float* w0gB, char* SWb, char* SXb, int tid, int wv, int llo,
    int lhi, const float* __restrict__ b_mu, int g, int mycol,
    float* __restrict__ out, float& regp) {
  const int rc = min(MC, cnt - mc);
  const int mts = (rc + 15) >> 4;  // active 16-row m-tiles (1..4)

  const int r0 = tid >> 3, kq = tid & 7;
  const int sq = (kq ^ (r0 & 7)) << 2;  // swizzled src offset (floats*4B idx)
  int slA = mc + r0;      if (slA >= cnt) slA = cnt - 1;  // dup; not stored
  int slB = mc + 32 + r0; if (slB >= cnt) slB = cnt - 1;
  const float* xgA = x + ((size_t)order[rs + slA] << 9) + sq;
  const float* xgB = x + ((size_t)order[rs + slB] << 9) + sq;

  f32x4 acc0 = {0.f, 0.f, 0.f, 0.f}, acc1 = {0.f, 0.f, 0.f, 0.f};
  f32x4 acc2 = {0.f, 0.f, 0.f, 0.f}, acc3 = {0.f, 0.f, 0.f, 0.f};
  f32x4 w0a0 = {0.f, 0.f, 0.f, 0.f}, w0a1 = {0.f, 0.f, 0.f, 0.f};
  f32x4 w0b0 = {0.f, 0.f, 0.f, 0.f}, w0b1 = {0.f, 0.f, 0.f, 0.f};

  // ---- prologue: batch1 = {stage0, w0(0)} | fence | batch2 = rest ----
  {
    char* dw = SWb + (wv << 10);
    char* dx = SXb + (wv << 10);
    gload16(wgA, dw);
    gload16(wgB, dw + 4096);
    gload16(xgA, dx);
    gload16(xgB, dx + 4096);
    if constexpr (DOREG) {
      w0a0 = *(const f32x4*)(w0gA);
      w0a1 = *(const f32x4*)(w0gB);
    }
    ISSUE_FENCE();  // step0's vmcnt(6) drains batch1 regardless of reorder
    dw = SWb + 8192 + (wv << 10);
    dx = SXb + 8192 + (wv << 10);
    gload16(wgA + BK, dw);
    gload16(wgB + BK, dw + 4096);
    gload16(xgA + BK, dx);
    gload16(xgB + BK, dx + 4096);
    if constexpr (DOREG) {
      w0b0 = *(const f32x4*)(w0gA + BK);
      w0b1 = *(const f32x4*)(w0gB + BK);
    }
    dw = SWb + 2 * 8192 + (wv << 10);
    dx = SXb + 2 * 8192 + (wv << 10);
    gload16(wgA + 2 * BK, dw);
    gload16(wgB + 2 * BK, dw + 4096);
    gload16(xgA + 2 * BK, dx);
    gload16(xgB + 2 * BK, dx + 4096);
  }

#define STEP(S)                                                            \
  step<S, DOREG>(SWb, SXb, wgA, wgB, xgA, xgB, w0gA, w0gB, w0a0, w0a1,     \
                 w0b0, w0b1, wv, llo, lhi, tid, mts, acc0, acc1, acc2,     \
                 acc3, regp)
  STEP(0);  STEP(1);  STEP(2);  STEP(3);
  STEP(4);  STEP(5);  STEP(6);  STEP(7);
  STEP(8);  STEP(9);  STEP(10); STEP(11);
  STEP(12); STEP(13); STEP(14); STEP(15);
#undef STEP

  // ---- epilogue: D row = 4*lhi + j, col = llo; scatter by order ----
  const float bias = b_mu[(g << 9) + mycol];
#define STORE_M(M, ACC)                                                    \
  if ((M) < mts) {                                                         \
    _Pragma("unroll") for (int j = 0; j < 4; ++j) {                        \
      const int slot = mc + ((M) << 4) + (lhi << 2) + j;                   \
      if (slot < cnt)                                                      \
        out[(size_t)order[rs + slot] * U_SZ + mycol] = ACC[j] + bias;      \
    }                                                                      \
  }
  STORE_M(0, acc0)
  STORE_M(1, acc1)
  STORE_M(2, acc2)
  STORE_M(3, acc3)
#undef STORE_M
}

// ---------------------------------------------------------------------------
// Kernel B: grouped GEMM (global_load_lds-staged MFMA) + fused reg loss +
// finalize.
// ---------------------------------------------------------------------------
__global__ __launch_bounds__(THREADS, 2) void gemm_kernel(
    const float* __restrict__ x, const float* __restrict__ w_mu,
    const float* __restrict__ b_mu, const float* __restrict__ w0_mu,
    const float* __restrict__ b0_mu, float* __restrict__ out,
    float* __restrict__ wsf, unsigned* __restrict__ done,
    const int* __restrict__ counts, const int* __restrict__ rowstart,
    const int* __restrict__ order) {
  // fp32 planes: 4 buffers x (W [64][32] + X [64][32]) = 64 KB.
  __shared__ __align__(16) char SW[4 * 8192];
  __shared__ __align__(16) char SX[4 * 8192];
  __shared__ float red_s[4];

  const int bid = blockIdx.x;
  const int g = bid & 63;   // bid%8 == g%8 -> a group's blocks share an XCD
  const int nt = bid >> 6;  // 64-col tile 0..7
  const int n0 = nt << 6;

  const int tid = threadIdx.x;
  const int lane = tid & 63;
  const int wv = tid >> 6;    // wave -> 16-col slice
  const int llo = lane & 15;  // frag row/col within 16-tile
  const int lhi = lane >> 4;  // frag k-subchunk

  const int cnt = counts[g];

  if (cnt > 0) {
    const int rs = rowstart[g];
    const int mycol = n0 + (wv << 4) + llo;
    const int r0 = tid >> 3, kq = tid & 7;
    const int sq = (kq ^ (r0 & 7)) << 2;  // rows r0 and 32+r0 share (row&7)
    const float* wgA =
        w_mu + ((size_t)g << 18) + ((size_t)(n0 + r0) << 9) + sq;
    const float* wgB =
        w_mu + ((size_t)g << 18) + ((size_t)(n0 + 32 + r0) << 9) + sq;
    const float* w0gA = w0_mu + ((size_t)(n0 + r0) << 9) + sq;
    const float* w0gB = w0_mu + ((size_t)(n0 + 32 + r0) << 9) + sq;

    float regp = 0.0f;
    if (nt == 0) {  // fused bias reg-loss, once per group
#pragma unroll
      for (int u = 0; u < 2; ++u) {
        const int idx = (u << 8) + tid;
        const float d = b_mu[(g << 9) + idx] - b0_mu[idx];
        regp += d * d;
      }
    }

    for (int mc = 0; mc < cnt; mc += MC) {  // one pass in practice (cnt<=64)
      if (mc == 0) {
        run_chunk<true>(x, order, rs, 0, cnt, wgA, wgB, w0gA, w0gB, SW, SX,
                        tid, wv, llo, lhi, b_mu, g, mycol, out, regp);
      } else {
        run_chunk<false>(x, order, rs, mc, cnt, wgA, wgB, w0gA, w0gB, SW, SX,
                         tid, wv, llo, lhi, b_mu, g, mycol, out, regp);
      }
    }

    // ---- block-reduce reg partials, weight by cnt, one atomic ----
#pragma unroll
    for (int o = 32; o > 0; o >>= 1) regp += __shfl_down(regp, o, 64);
    if (lane == 0) red_s[wv] = regp;
    __syncthreads();
    if (tid == 0)
      atomicAdd(wsf, (float)cnt * (red_s[0] + red_s[1] + red_s[2] + red_s[3]));
  }

  // fused finalize: last block writes the reg-loss scalar
  if (tid == 0) {
    __threadfence();
    if (atomicAdd(done, 1u) == (unsigned)(NBLOCKS - 1)) {
      const float v = atomicAdd(wsf, 0.0f);  // coherent device-scope read
      out[(size_t)B_SZ * U_SZ] = REG_STRENGTH * v;
    }
  }
}

extern "C" void kernel_launch(void* const* d_in, const int* in_sizes, int n_in,
                              void* d_out, int out_size, void* d_ws,
                              size_t ws_size, hipStream_t stream) {
  (void)in_sizes; (void)n_in; (void)out_size; (void)ws_size;
  const float* x     = (const float*)d_in[0];
  const int*   gid   = (const int*)d_in[1];
  const float* w_mu  = (const float*)d_in[2];
  const float* b_mu  = (const float*)d_in[3];
  const float* w0_mu = (const float*)d_in[4];
  const float* b0_mu = (const float*)d_in[5];

  float*    wsf      = (float*)d_ws;         // [0]
  unsigned* done     = (unsigned*)d_ws + 1;  // [1]
  int*      counts   = (int*)d_ws + 2;
  int*      rowstart = (int*)d_ws + 2 + G_SZ;
  int*      order    = (int*)d_ws + 2 + 2 * G_SZ;

  prep_kernel<<<1, 1024, 0, stream>>>(gid, counts, rowstart, order, wsf, done);
  gemm_kernel<<<NBLOCKS, THREADS, 0, stream>>>(
      x, w_mu, b_mu, w0_mu, b0_mu, (float*)d_out, wsf, done,
      counts, rowstart, order);
}

// Round 9
// 153.923 us; speedup vs baseline: 1.2869x; 1.0895x over previous
//
#include <hip/hip_runtime.h>

// Problem constants (B=2048, F=512, U=512, G=64, REG_STRENGTH=1.0)
#define B_SZ 2048
#define F_SZ 512
#define U_SZ 512
#define G_SZ 64
#define REG_STRENGTH 1.0f

// prep: histogram/prefix(shfl-scan)/scatter + workspace zeroing.
// gemm: r4's PROVEN codegen pattern (plain __syncthreads, single-set register
//   prefetch, stage-side bf16 hi/lo split -- the only structure that never
//   produced scratch traffic: VGPR 108, WRITE 4.1 MB), re-tiled for TLP:
//   block = (group g, 32-col tile ct), 256 thr = 4 waves, BK=32, LDS 24 KB
//   -> 4 independent blocks (4 barrier domains) per CU instead of r4's 2.
//   When one block sits in its barrier's vmcnt drain, three others issue.
//   r5-r8 lesson: pipeline state carried across asm-volatile barriers is
//   materialized in scratch by this compiler (70-110 MB/dispatch) -- avoided
//   entirely here.
#define THREADS 256
#define NCT 16                  // 32-col tiles per group
#define NBLOCKS (G_SZ * NCT)    // 1024; bid%8==g%8 -> group's blocks share XCD
#define MC 64                   // M rows per chunk (cnt ~ Binom(2048,1/64) ~ 32)
#define BK 32                   // K per step (one MFMA k-slice)
#define NSTEP (F_SZ / BK)       // 16

typedef float f32x4 __attribute__((ext_vector_type(4)));
typedef __bf16 bf16x8 __attribute__((ext_vector_type(8)));

#define MFMA(a, b, c) __builtin_amdgcn_mfma_f32_16x16x32_bf16((a), (b), (c), 0, 0, 0)

// fp32 -> (hi, lo) bf16 split (RNE). Dropped lo*lo matmul term is O(2^-18):
// fp32-grade accuracy (absmax 0.015625 every round since r1).
static __device__ __forceinline__ void split4(const f32x4 v, ushort4* h,
                                              ushort4* l) {
  unsigned short hb[4], lb[4];
#pragma unroll
  for (int i = 0; i < 4; ++i) {
    const __bf16 t = (__bf16)v[i];
    hb[i] = __builtin_bit_cast(unsigned short, t);
    lb[i] = __builtin_bit_cast(unsigned short, (__bf16)(v[i] - (float)t));
  }
  *h = make_ushort4(hb[0], hb[1], hb[2], hb[3]);
  *l = make_ushort4(lb[0], lb[1], lb[2], lb[3]);
}

// Stage one f32x4 into hi/lo LDS planes. Rows are 64 B (32 bf16); XOR
// swizzle byte ^= ((row>>1)&3)<<4 spreads the 16-row fragment-read column
// across the 4 16B-windows of the row (2-way residual = free), and the
// same XOR on the write side keeps layout consistent (rule #21 analog).
static __device__ __forceinline__ void stage4(unsigned short* __restrict__ H,
                                              unsigned short* __restrict__ L,
                                              int row, int kq, const f32x4 v) {
  int byte = (row << 6) + (kq << 3);
  byte ^= ((row >> 1) & 3) << 4;
  ushort4 h, l;
  split4(v, &h, &l);
  *(ushort4*)((char*)H + byte) = h;
  *(ushort4*)((char*)L + byte) = l;
}

// Swizzled byte offset of a 16B fragment window (row, lhi).
static __device__ __forceinline__ int fragoff(int row, int lhi) {
  int byte = (row << 6) + (lhi << 4);
  byte ^= ((row >> 1) & 3) << 4;
  return byte;
}

// ---------------------------------------------------------------------------
// Kernel A: histogram -> shfl scan -> scatter; zeroes wsf/done.
// ---------------------------------------------------------------------------
__global__ __launch_bounds__(1024) void prep_kernel(
    const int* __restrict__ gid, int* __restrict__ counts,
    int* __restrict__ rowstart, int* __restrict__ order,
    float* __restrict__ wsf, unsigned* __restrict__ done) {
  __shared__ int cnt_s[G_SZ];
  __shared__ int cur_s[G_SZ];
  const int tid = threadIdx.x;

  if (tid < G_SZ) cnt_s[tid] = 0;
  if (tid == 0) { wsf[0] = 0.0f; *done = 0u; }
  __syncthreads();

  for (int b = tid; b < B_SZ; b += 1024) atomicAdd(&cnt_s[gid[b]], 1);
  __syncthreads();

  if (tid < G_SZ) {  // wave 0: shfl inclusive scan -> exclusive
    const int c = cnt_s[tid];
    int inc = c;
#pragma unroll
    for (int o = 1; o < G_SZ; o <<= 1) {
      const int t = __shfl_up(inc, o, 64);
      if (tid >= o) inc += t;
    }
    counts[tid] = c;
    rowstart[tid] = inc - c;
    cur_s[tid] = inc - c;
  }
  __syncthreads();

  for (int b = tid; b < B_SZ; b += 1024) {
    int pos = atomicAdd(&cur_s[gid[b]], 1);
    order[pos] = b;
  }
}

// ---------------------------------------------------------------------------
// Kernel B: grouped GEMM (LDS-staged MFMA, TLP-hidden latency) + fused reg
// loss + finalize.
// ---------------------------------------------------------------------------
__global__ __launch_bounds__(THREADS, 4) void gemm_kernel(
    const float* __restrict__ x, const float* __restrict__ w_mu,
    const float* __restrict__ b_mu, const float* __restrict__ w0_mu,
    const float* __restrict__ b0_mu, float* __restrict__ out,
    float* __restrict__ wsf, unsigned* __restrict__ done,
    const int* __restrict__ counts, const int* __restrict__ rowstart,
    const int* __restrict__ order) {
  // bf16 planes, 64 B rows, double-buffered:
  //   W: 32 rows x 32 k -> 2 KB/plane/buf; X: 64 rows x 32 k -> 4 KB.
  //   (2+2+4+4) KB x 2 bufs = 24 KB -> 4 blocks/CU (with VGPR <= 128).
  __shared__ __align__(16) unsigned short WHs[2][32 * BK];
  __shared__ __align__(16) unsigned short WLs[2][32 * BK];
  __shared__ __align__(16) unsigned short XHs[2][MC * BK];
  __shared__ __align__(16) unsigned short XLs[2][MC * BK];
  __shared__ float red_s[4];

  const int bid = blockIdx.x;
  const int g = bid & 63;   // bid%8 == g%8 -> a group's blocks share an XCD
  const int ct = bid >> 6;  // 32-col tile 0..15
  const int n0 = ct << 5;

  const int tid = threadIdx.x;
  const int lane = tid & 63;
  const int wv = tid >> 6;
  const int mh = wv >> 1;     // wave's m-tile pair (0: tiles 0-1, 1: 2-3)
  const int chalf = wv & 1;   // wave's 16-col half of the 32-col tile
  const int llo = lane & 15;  // frag row/col within 16-tile
  const int lhi = lane >> 4;  // frag k-subchunk

  const int srow = tid >> 3;  // staging row 0..31 (X adds +32 for 2nd quad)
  const int kq = tid & 7;     // staging float4 within 32-k row (coalesced)

  const int cnt = counts[g];

  if (cnt > 0) {
    const int rs = rowstart[g];
    const int mycol = n0 + (chalf << 4) + llo;
    const float* __restrict__ wgp =
        w_mu + ((size_t)g << 18) + ((size_t)(n0 + srow) << 9) + (kq << 2);
    const float* __restrict__ w0p =
        w0_mu + ((size_t)(n0 + srow) << 9) + (kq << 2);

    float regp = 0.0f;
    if (ct == 0) {  // fused bias reg-loss, once per group
#pragma unroll
      for (int u = 0; u < 2; ++u) {
        const int idx = (u << 8) + tid;
        const float d = b_mu[(g << 9) + idx] - b0_mu[idx];
        regp += d * d;
      }
    }

    for (int mc = 0; mc < cnt; mc += MC) {  // one pass in practice (cnt<=64)
      const int rc = min(MC, cnt - mc);
      const int mts = (rc + 15) >> 4;  // active 16-row m-tiles (1..4)
      const bool doreg = (mc == 0);

      int slA = mc + srow;      if (slA >= cnt) slA = cnt - 1;  // dup; unstored
      int slB = mc + 32 + srow; if (slB >= cnt) slB = cnt - 1;
      const float* __restrict__ xpA =
          x + ((size_t)order[rs + slA] << 9) + (kq << 2);
      const float* __restrict__ xpB =
          x + ((size_t)order[rs + slB] << 9) + (kq << 2);

      f32x4 acc0 = {0.f, 0.f, 0.f, 0.f};
      f32x4 acc1 = {0.f, 0.f, 0.f, 0.f};

      // ---- prologue: coalesced load + stage step 0 into buffer 0 ----
      f32x4 wr = *(const f32x4*)(wgp);
      f32x4 xrA = *(const f32x4*)(xpA);
      f32x4 xrB = *(const f32x4*)(xpB);
      if (doreg) {
        const f32x4 z = *(const f32x4*)(w0p);
#pragma unroll
        for (int i = 0; i < 4; ++i) {
          const float d = wr[i] - z[i];
          regp += d * d;
        }
      }
      stage4(WHs[0], WLs[0], srow, kq, wr);
      stage4(XHs[0], XLs[0], srow, kq, xrA);
      stage4(XHs[0], XLs[0], srow + 32, kq, xrB);
      __syncthreads();

#pragma unroll 2
      for (int s = 0; s < NSTEP; ++s) {
        const int p = s & 1;
        // (1) issue next step's coalesced loads (land during compute)
        if (s + 1 < NSTEP) {
          const int ko = (s + 1) << 5;
          wr = *(const f32x4*)(wgp + ko);
          xrA = *(const f32x4*)(xpA + ko);
          xrB = *(const f32x4*)(xpB + ko);
        }
        // (2) compute on buffer p: fragments from swizzled LDS
        __builtin_amdgcn_s_setprio(1);
        {
          const int wrow = (chalf << 4) + llo;
          const bf16x8 wh =
              *(const bf16x8*)((const char*)WHs[p] + fragoff(wrow, lhi));
          const bf16x8 wl =
              *(const bf16x8*)((const char*)WLs[p] + fragoff(wrow, lhi));
          const int m0 = mh << 1;
          if (m0 < mts) {
            const int ar = (m0 << 4) + llo;
            const bf16x8 ah =
                *(const bf16x8*)((const char*)XHs[p] + fragoff(ar, lhi));
            const bf16x8 al =
                *(const bf16x8*)((const char*)XLs[p] + fragoff(ar, lhi));
            acc0 = MFMA(ah, wh, acc0);
            acc0 = MFMA(ah, wl, acc0);
            acc0 = MFMA(al, wh, acc0);
          }
          if (m0 + 1 < mts) {
            const int ar = ((m0 + 1) << 4) + llo;
            const bf16x8 ah =
                *(const bf16x8*)((const char*)XHs[p] + fragoff(ar, lhi));
            const bf16x8 al =
                *(const bf16x8*)((const char*)XLs[p] + fragoff(ar, lhi));
            acc1 = MFMA(ah, wh, acc1);
            acc1 = MFMA(ah, wl, acc1);
            acc1 = MFMA(al, wh, acc1);
          }
        }
        __builtin_amdgcn_s_setprio(0);
        // (3) reg-loss + stage prefetched regs into the other buffer
        if (s + 1 < NSTEP) {
          if (doreg) {
            const f32x4 z = *(const f32x4*)(w0p + ((s + 1) << 5));
#pragma unroll
            for (int i = 0; i < 4; ++i) {
              const float d = wr[i] - z[i];
              regp += d * d;
            }
          }
          const int q = p ^ 1;
          stage4(WHs[q], WLs[q], srow, kq, wr);
          stage4(XHs[q], XLs[q], srow, kq, xrA);
          stage4(XHs[q], XLs[q], srow + 32, kq, xrB);
        }
        __syncthreads();
      }

      // ---- epilogue: D row = 4*lhi + j, col = llo; scatter by order ----
      const float bias = b_mu[(g << 9) + mycol];
      const int m0 = mh << 1;
      if (m0 < mts) {
#pragma unroll
        for (int j = 0; j < 4; ++j) {
          const int slot = mc + (m0 << 4) + (lhi << 2) + j;
          if (slot < cnt) {
            out[(size_t)order[rs + slot] * U_SZ + mycol] = acc0[j] + bias;
          }
        }
      }
      if (m0 + 1 < mts) {
#pragma unroll
        for (int j = 0; j < 4; ++j) {
          const int slot = mc + ((m0 + 1) << 4) + (lhi << 2) + j;
          if (slot < cnt) {
            out[(size_t)order[rs + slot] * U_SZ + mycol] = acc1[j] + bias;
          }
        }
      }
    }

    // ---- block-reduce reg partials, weight by cnt, one atomic ----
#pragma unroll
    for (int o = 32; o > 0; o >>= 1) regp += __shfl_down(regp, o, 64);
    if (lane == 0) red_s[wv] = regp;
    __syncthreads();
    if (tid == 0)
      atomicAdd(wsf, (float)cnt * (red_s[0] + red_s[1] + red_s[2] + red_s[3]));
  }

  // fused finalize: last block writes the reg-loss scalar
  if (tid == 0) {
    __threadfence();
    if (atomicAdd(done, 1u) == (unsigned)(NBLOCKS - 1)) {
      const float v = atomicAdd(wsf, 0.0f);  // coherent device-scope read
      out[(size_t)B_SZ * U_SZ] = REG_STRENGTH * v;
    }
  }
}

extern "C" void kernel_launch(void* const* d_in, const int* in_sizes, int n_in,
                              void* d_out, int out_size, void* d_ws,
                              size_t ws_size, hipStream_t stream) {
  (void)in_sizes; (void)n_in; (void)out_size; (void)ws_size;
  const float* x     = (const float*)d_in[0];
  const int*   gid   = (const int*)d_in[1];
  const float* w_mu  = (const float*)d_in[2];
  const float* b_mu  = (const float*)d_in[3];
  const float* w0_mu = (const float*)d_in[4];
  const float* b0_mu = (const float*)d_in[5];

  float*    wsf      = (float*)d_ws;         // [0]
  unsigned* done     = (unsigned*)d_ws + 1;  // [1]
  int*      counts   = (int*)d_ws + 2;
  int*      rowstart = (int*)d_ws + 2 + G_SZ;
  int*      order    = (int*)d_ws + 2 + 2 * G_SZ;

  prep_kernel<<<1, 1024, 0, stream>>>(gid, counts, rowstart, order, wsf, done);
  gemm_kernel<<<NBLOCKS, THREADS, 0, stream>>>(
      x, w_mu, b_mu, w0_mu, b0_mu, (float*)d_out, wsf, done,
      counts, rowstart, order);
}